// Round 11
// baseline (171.392 us; speedup 1.0000x reference)
//
#include <hip/hip_runtime.h>
#include <hip/hip_bf16.h>

#define VOCABN 50000
#define BN 128
#define CN 5
#define HN 50
#define LN 32
#define DN 300
#define DP 320     // padded K
#define KNN 20

typedef __bf16    bf16x8 __attribute__((ext_vector_type(8)));
typedef float     f32x4  __attribute__((ext_vector_type(4)));
typedef ushort    u16x8  __attribute__((ext_vector_type(8)));

#if __has_builtin(__builtin_amdgcn_exp2f)
#define FEXP2 __builtin_amdgcn_exp2f
#else
#define FEXP2 exp2f
#endif
#if __has_builtin(__builtin_amdgcn_logf)
#define FLOG2 __builtin_amdgcn_logf
#else
#define FLOG2 log2f
#endif

#define LOG2E 1.4426950408889634f
#define LN2F  0.6931471805599453f

// ---------------- kernel 1: normalize vocab -> bf16 table, wave-per-row ----------------
__global__ __launch_bounds__(256) void knorm_embed2(const float* __restrict__ emb,
                                                    ushort* __restrict__ tabo) {
    const int t    = threadIdx.x;
    const int lane = t & 63;
    const int w    = t >> 6;
    const int v    = blockIdx.x * 4 + w;          // grid 12500 x 4 waves
    const float* row = emb + (size_t)v * DN;
    const float4* r4 = (const float4*)row;        // 75 float4 per row

    float4 x = r4[lane];                          // floats 4*lane .. +4 (max 255 < 300)
    float ss = x.x * x.x + x.y * x.y + x.z * x.z + x.w * x.w;
    if (lane < 11) {                              // floats 256..299
        float4 y = r4[64 + lane];
        ss += y.x * y.x + y.y * y.y + y.z * y.z + y.w * y.w;
    }
    #pragma unroll
    for (int off = 32; off; off >>= 1) ss += __shfl_xor(ss, off);
    const float scale = 1.0f / fmaxf(sqrtf(ss), 1e-8f);

    if (lane < 40) {                              // 40 x int4 = 320 bf16 out
        u16x8 u;
        #pragma unroll
        for (int j = 0; j < 8; ++j) {
            int e = lane * 8 + j;
            float f = (e < DN) ? row[e] * scale : 0.f;   // L1-hot reload
            __hip_bfloat16 h = __float2bfloat16(f);
            u[j] = *(ushort*)&h;
        }
        *(u16x8*)(tabo + (size_t)v * DP + lane * 8) = u;
    }
}

// Slice buffers: [row][64 ushorts] = 128B rows; 16B chunks XOR-swizzled (R6-proven).
__device__ inline bf16x8 ldfrag(const ushort* buf, int row, int chunk) {
    int pos = chunk ^ (row & 7);
    return *(const bf16x8*)((const char*)buf + row * 128 + pos * 16);
}

// ---------------- kernel 2: fused GEMM + factorized kernel-pooling ----------------
// GEMM: R6-proven skeleton (5 K-slices of 64, XOR-swizzled Bbuf, 10 barriers),
// acc[2][10] in AGPRs, A direct-from-global with 1-slice prefetch.
// Pool: per (at,hl) tile -> wave-private f32 simbuf (stride 33, <=2-way banks),
// factorized Gaussians (4 exp2/elem), 4-lane DPP Q-reduce, zero barriers.
__global__ __launch_bounds__(320, 3) void knrm_fused3(const int* __restrict__ cand,
                                                      const int* __restrict__ clik,
                                                      const ushort* __restrict__ tab,
                                                      const float* __restrict__ ltr_w,
                                                      float* __restrict__ score) {
    __shared__ __align__(16) ushort Bbuf[160 * 64];   // 20 KB
    __shared__ __align__(16) float  simbuf[5][16 * 33]; // 10.6 KB, wave-private bands
    __shared__ int tokA[160];
    __shared__ int tokB[160];

    const int t    = threadIdx.x;
    const int lane = t & 63;
    const int w    = t >> 6;          // wave 0..4 == candidate c
    // T1: bijective XCD swizzle (grid 1280 = 8 x 160)
    const int bid  = (blockIdx.x & 7) * 160 + (blockIdx.x >> 3);
    const int b    = bid / 10;
    const int hc   = bid % 10;

    if (t < 160) tokA[t] = cand[b * (CN * LN) + t];
    else         tokB[t - 160] = clik[b * (HN * LN) + hc * 160 + (t - 160)];
    __syncthreads();

    const int m15 = lane & 15;
    const int g4  = lane >> 4;

    // A direct-gather bases (wave-private rows)
    const char* sA0 = (const char*)tab + (size_t)tokA[w * 32 + m15]      * (DP * 2) + g4 * 16;
    const char* sA1 = (const char*)tab + (size_t)tokA[w * 32 + 16 + m15] * (DP * 2) + g4 * 16;

    f32x4 acc[2][10];
    #pragma unroll
    for (int at = 0; at < 2; ++at)
        #pragma unroll
        for (int jg = 0; jg < 10; ++jg)
            acc[at][jg] = (f32x4){0.f, 0.f, 0.f, 0.f};

    // prologue: slice-0 A frags
    bf16x8 a00 = *(const bf16x8*)(sA0);
    bf16x8 a01 = *(const bf16x8*)(sA0 + 64);
    bf16x8 a10 = *(const bf16x8*)(sA1);
    bf16x8 a11 = *(const bf16x8*)(sA1 + 64);

    #pragma unroll 1
    for (int ss = 0; ss < 5; ++ss) {
        __syncthreads();                          // Bbuf free
        {   // stage B: 1280 chunks of 16B, 4 per thread (R6-proven, pre-swizzled src)
            int4 rg[4];
            #pragma unroll
            for (int it = 0; it < 4; ++it) {
                int cid = it * 320 + t, row = cid >> 3, c = cid & 7;
                rg[it] = *(const int4*)((const char*)tab +
                    (size_t)tokB[row] * (DP * 2) + ss * 128 + ((c ^ (row & 7)) << 4));
            }
            #pragma unroll
            for (int it = 0; it < 4; ++it) {
                int cid = it * 320 + t, row = cid >> 3, c = cid & 7;
                *(int4*)((char*)Bbuf + row * 128 + c * 16) = rg[it];
            }
        }
        __syncthreads();                          // Bbuf ready

        bf16x8 n00 = a00, n01 = a01, n10 = a10, n11 = a11;
        if (ss < 4) {                             // prefetch next A frags; hide under MFMA
            const int ko = (ss + 1) * 128;
            n00 = *(const bf16x8*)(sA0 + ko);
            n01 = *(const bf16x8*)(sA0 + ko + 64);
            n10 = *(const bf16x8*)(sA1 + ko);
            n11 = *(const bf16x8*)(sA1 + ko + 64);
        }
        #pragma unroll
        for (int jg = 0; jg < 10; ++jg) {         // kc = 0
            bf16x8 bf = ldfrag(Bbuf, jg * 16 + m15, g4);
            acc[0][jg] = __builtin_amdgcn_mfma_f32_16x16x32_bf16(a00, bf, acc[0][jg], 0, 0, 0);
            acc[1][jg] = __builtin_amdgcn_mfma_f32_16x16x32_bf16(a10, bf, acc[1][jg], 0, 0, 0);
        }
        #pragma unroll
        for (int jg = 0; jg < 10; ++jg) {         // kc = 1
            bf16x8 bf = ldfrag(Bbuf, jg * 16 + m15, 4 + g4);
            acc[0][jg] = __builtin_amdgcn_mfma_f32_16x16x32_bf16(a01, bf, acc[0][jg], 0, 0, 0);
            acc[1][jg] = __builtin_amdgcn_mfma_f32_16x16x32_bf16(a11, bf, acc[1][jg], 0, 0, 0);
        }
        a00 = n00; a01 = n01; a10 = n10; a11 = n11;
    }

    // ---- fused pooling (R5 factorization), wave-private, barrier-free ----
    const float C1   = 10.0f * LOG2E;       // t  = 2^( C1*s)
    const float C2   = -50.0f * LOG2E;      // e0 = 2^( C2*s^2)
    const float AK19 = 849.3218002880191f;  // sqrt(LOG2E / (2*0.001^2))
    static const float CkT[10] = {          // e^{-m^2/2}; k unrolled -> folds to constants
        1.0f, 0.6065306597126334f, 0.1353352832366127f, 0.011108996538242306f,
        3.3546262790251185e-4f, 3.7266531720786709e-6f, 1.5229979744712628e-8f,
        2.2897348456191135e-11f, 1.2664165549094176e-14f, 2.576757109154981e-18f };

    float* sb = &simbuf[w][0];                    // [16][33] f32, wave-private
    const int   rr = lane >> 2;                   // read row 0..15
    const float* sp0 = sb + rr * 33 + (lane & 3) * 8;
    float res = 0.f;

    #pragma unroll
    for (int at = 0; at < 2; ++at) {
        #pragma unroll
        for (int hl = 0; hl < 5; ++hl) {
            // dump tile: C/D layout col=lane&15, row=(lane>>4)*4+reg [m89-verified]
            #pragma unroll
            for (int jgl = 0; jgl < 2; ++jgl)
                #pragma unroll
                for (int r = 0; r < 4; ++r)
                    sb[(g4 * 4 + r) * 33 + jgl * 16 + m15] = acc[at][2 * hl + jgl][r];
            // wave-internal lgkmcnt ordering makes writes visible to the reads below

            float Q[KNN];
            #pragma unroll
            for (int k = 0; k < KNN; ++k) Q[k] = 0.f;
            #pragma unroll
            for (int e = 0; e < 8; ++e) {
                float s  = sp0[e];
                float cs = C1 * s;
                float tt = FEXP2(cs);
                float uu = FEXP2(-cs);
                float e0 = FEXP2(C2 * (s * s));
                Q[9] += e0;
                float ap = e0, am = e0;
                ap *= tt;  Q[10] += ap;   am *= uu;  Q[8] += am;
                ap *= tt;  Q[11] += ap;   am *= uu;  Q[7] += am;
                ap *= tt;  Q[12] += ap;   am *= uu;  Q[6] += am;
                ap *= tt;  Q[13] += ap;   am *= uu;  Q[5] += am;
                ap *= tt;  Q[14] += ap;   am *= uu;  Q[4] += am;
                ap *= tt;  Q[15] += ap;   am *= uu;  Q[3] += am;
                ap *= tt;  Q[16] += ap;   am *= uu;  Q[2] += am;
                ap *= tt;  Q[17] += ap;   am *= uu;  Q[1] += am;
                ap *= tt;  Q[18] += ap;   am *= uu;  Q[0] += am;
                float d = fmaf(s, AK19, -AK19);   // (s-1)*AK19
                Q[19] += FEXP2(-(d * d));         // sharp sigma=0.001 kernel
            }
            // reduce Q across the 4 lanes sharing this row (xor 1,2 -> DPP quad perms)
            #pragma unroll
            for (int k = 0; k < KNN; ++k) {
                Q[k] += __shfl_xor(Q[k], 1);
                Q[k] += __shfl_xor(Q[k], 2);
            }
            const float* wrow = ltr_w + (hc * 5 + hl) * KNN;
            float rs = 0.f;
            #pragma unroll
            for (int k = 0; k < KNN - 1; ++k) {
                int ai = (k < 9) ? (9 - k) : (k - 9);
                rs += wrow[k] * FLOG2(fmaxf(Q[k] * CkT[ai], 1e-10f));
            }
            rs += wrow[KNN - 1] * FLOG2(fmaxf(Q[KNN - 1], 1e-10f));
            res += rs;
        }
    }

    // each row counted by 4 lanes -> x0.25; log2 -> ln
    res *= 0.25f * LN2F;
    #pragma unroll
    for (int off = 32; off; off >>= 1) res += __shfl_xor(res, off);
    if (lane == 0) atomicAdd(&score[b * CN + w], res);
}

// ---------------- kernel 3: log_softmax over C (ltr_b cancels) ----------------
__global__ __launch_bounds__(128) void knrm_final(const float* __restrict__ score,
                                                  float* __restrict__ out) {
    int b = threadIdx.x;
    if (b < BN) {
        float s[CN];
        float m = -1e30f;
        #pragma unroll
        for (int c = 0; c < CN; ++c) { s[c] = score[b * CN + c]; m = fmaxf(m, s[c]); }
        float sum = 0.f;
        #pragma unroll
        for (int c = 0; c < CN; ++c) sum += FEXP2((s[c] - m) * LOG2E);
        float lse = m + FLOG2(sum) * LN2F;
        #pragma unroll
        for (int c = 0; c < CN; ++c) out[b * CN + c] = s[c] - lse;
    }
}

extern "C" void kernel_launch(void* const* d_in, const int* in_sizes, int n_in,
                              void* d_out, int out_size, void* d_ws, size_t ws_size,
                              hipStream_t stream) {
    const int*   cand  = (const int*)d_in[0];   // [B,C,L]
    const int*   clik  = (const int*)d_in[1];   // [B,H,L]
    const float* emb   = (const float*)d_in[2]; // [VOCAB,D]
    const float* ltr_w = (const float*)d_in[3]; // [1,H*KN]
    float* out = (float*)d_out;

    const size_t TAB_B = (size_t)VOCABN * DP * 2;   // 32,000,000

    ushort* tab  = (ushort*)d_ws;
    float*  scre = (float*)((char*)d_ws + TAB_B);

    hipMemsetAsync(scre, 0, BN * CN * sizeof(float), stream);
    knorm_embed2<<<VOCABN / 4, 256, 0, stream>>>(emb, tab);
    knrm_fused3<<<BN * 10, 320, 0, stream>>>(cand, clik, tab, ltr_w, scre);
    knrm_final<<<1, 128, 0, stream>>>(scre, out);
}